// Round 1
// baseline (50.975 us; speedup 1.0000x reference)
//
#include <hip/hip_runtime.h>

// Problem constants
//   N=16 samples, C=256 content channels, S=512 style channels, HW=64x64
//
// Algebraic reduction of the reference:
//   k[n][3][3]  = conv(style[n], dw_w) + dw_b               (9 scalars / sample)
//   s_d[n][c]   = mean over 4x4 of style[n][c]
//   pw1[n]      = s_d[n] . pw_kn_w + pw_kn_b                (1 scalar / sample)
//   bias[n][o]  = s_d[n] . pw_bias_w[o] + pw_bias_b[o]
//   Xs[n][h][w] = sum_c content[n][c][h][w]                 (channel sum)
//   D[n][h][w]  = 3x3 reflect-pad conv of Xs with k[n]
//   out[n][o][h][w] = 256*pw1[n]*D[n][h][w] + bias[n][o]

// workspace layout (floats)
#define OFF_SCALE 0                         // 16      : 256*pw1[n]
#define OFF_K     16                        // 16*9    : k[n][9]
#define OFF_BIAS  160                       // 16*256  : bias[n][o]
#define OFF_XP    4256                      // 16*8*4096 : channel-sum partials
#define OFF_E     (4256 + 16*8*4096)        // 16*4096 : E[n][p] = scale*D

// ---------------------------------------------------------------- kernel A
__global__ __launch_bounds__(256) void ada_stats(
    const float* __restrict__ style,      // (16,512,4,4)
    const float* __restrict__ dw_w,       // (1,512,2,2)
    const float* __restrict__ dw_b,       // (1,)
    const float* __restrict__ pw_kn_w,    // (1,512,1,1)
    const float* __restrict__ pw_kn_b,    // (1,)
    const float* __restrict__ pw_bias_w,  // (256,512,1,1)
    const float* __restrict__ pw_bias_b,  // (256,)
    float* __restrict__ ws)
{
    const int n = blockIdx.x, t = threadIdx.x;
    __shared__ float sd[512];
    __shared__ float red[4][10];

    float acc[10];
#pragma unroll
    for (int j = 0; j < 10; ++j) acc[j] = 0.f;

#pragma unroll
    for (int cc = 0; cc < 2; ++cc) {
        const int c = t + cc * 256;
        const float4* sp = (const float4*)(style + ((size_t)n * 512 + c) * 16);
        float v[16];
#pragma unroll
        for (int q = 0; q < 4; ++q) {
            float4 f = sp[q];
            v[q*4+0] = f.x; v[q*4+1] = f.y; v[q*4+2] = f.z; v[q*4+3] = f.w;
        }
        float sum = 0.f;
#pragma unroll
        for (int q = 0; q < 16; ++q) sum += v[q];
        const float sdc = sum * 0.0625f;   // mean over 4x4
        sd[c] = sdc;

        const float* w = dw_w + c * 4;     // [a*2+b]
        const float w00 = w[0], w01 = w[1], w10 = w[2], w11 = w[3];
#pragma unroll
        for (int ki = 0; ki < 3; ++ki)
#pragma unroll
            for (int kj = 0; kj < 3; ++kj)
                acc[ki*3+kj] += v[ki*4 + kj]       * w00
                              + v[ki*4 + kj + 1]   * w01
                              + v[(ki+1)*4 + kj]   * w10
                              + v[(ki+1)*4 + kj+1] * w11;
        acc[9] += sdc * pw_kn_w[c];
    }

    // wave(64)-level butterfly reduce of the 10 partials
#pragma unroll
    for (int off = 32; off >= 1; off >>= 1)
#pragma unroll
        for (int j = 0; j < 10; ++j)
            acc[j] += __shfl_down(acc[j], off, 64);

    if ((t & 63) == 0) {
#pragma unroll
        for (int j = 0; j < 10; ++j) red[t >> 6][j] = acc[j];
    }
    __syncthreads();

    if (t < 10) {
        const float s = red[0][t] + red[1][t] + red[2][t] + red[3][t];
        if (t < 9) ws[OFF_K + n * 9 + t] = s + dw_b[0];
        else       ws[OFF_SCALE + n]     = 256.f * (s + pw_kn_b[0]);
    }

    // bias[n][t] = sd . pw_bias_w[t] + pw_bias_b[t]
    float a2 = 0.f;
    const float4* wrow = (const float4*)(pw_bias_w + (size_t)t * 512);
#pragma unroll 4
    for (int c4 = 0; c4 < 128; ++c4) {
        float4 f = wrow[c4];
        a2 += sd[c4*4+0]*f.x + sd[c4*4+1]*f.y + sd[c4*4+2]*f.z + sd[c4*4+3]*f.w;
    }
    ws[OFF_BIAS + n * 256 + t] = a2 + pw_bias_b[t];
}

// ---------------------------------------------------------------- kernel B
// channel-sum partials: Xp[n][g][p] = sum_{c in group g (32 ch)} content[n][c][p]
__global__ __launch_bounds__(256) void ada_chsum(
    const float* __restrict__ content,    // (16,256,64,64)
    float* __restrict__ ws)
{
    const int b  = blockIdx.x;            // 512 blocks
    const int n  = b >> 5;
    const int g  = (b >> 2) & 7;
    const int pt = b & 3;
    const int p  = pt * 1024 + threadIdx.x * 4;

    const float4* src = (const float4*)(content + ((size_t)(n * 256 + g * 32)) * 4096 + p);
    float4 a = make_float4(0.f, 0.f, 0.f, 0.f);
#pragma unroll 8
    for (int c = 0; c < 32; ++c) {
        float4 v = src[(size_t)c * 1024];
        a.x += v.x; a.y += v.y; a.z += v.z; a.w += v.w;
    }
    *(float4*)(ws + OFF_XP + ((size_t)(n * 8 + g)) * 4096 + p) = a;
}

// ---------------------------------------------------------------- kernel C
// E[n][p] = scale[n] * (3x3 reflect conv of Xs with k[n])
__global__ __launch_bounds__(256) void ada_conv(float* __restrict__ ws)
{
    const int n = blockIdx.x, t = threadIdx.x;
    __shared__ float Xs[64][64];

    const float* Xp = ws + OFF_XP + (size_t)n * 8 * 4096;
#pragma unroll
    for (int r = 0; r < 16; ++r) {
        const int p = r * 256 + t;
        float s = 0.f;
#pragma unroll
        for (int g = 0; g < 8; ++g) s += Xp[g * 4096 + p];
        Xs[p >> 6][p & 63] = s;
    }

    float k[9];
#pragma unroll
    for (int j = 0; j < 9; ++j) k[j] = ws[OFF_K + n * 9 + j];
    const float scale = ws[OFF_SCALE + n];
    __syncthreads();

#pragma unroll
    for (int r = 0; r < 16; ++r) {
        const int p = r * 256 + t, h = p >> 6, w = p & 63;
        float d = 0.f;
#pragma unroll
        for (int ki = 0; ki < 3; ++ki) {
            int hh = h + ki - 1;
            hh = hh < 0 ? 1 : (hh > 63 ? 62 : hh);   // reflect (no edge repeat)
#pragma unroll
            for (int kj = 0; kj < 3; ++kj) {
                int wwi = w + kj - 1;
                wwi = wwi < 0 ? 1 : (wwi > 63 ? 62 : wwi);
                d += k[ki*3+kj] * Xs[hh][wwi];
            }
        }
        ws[OFF_E + n * 4096 + p] = scale * d;
    }
}

// ---------------------------------------------------------------- kernel D
// out[n][o][p] = E[n][p] + bias[n][o]
__global__ __launch_bounds__(256) void ada_out(
    const float* __restrict__ ws, float4* __restrict__ out)
{
    const int idx   = blockIdx.x * 256 + threadIdx.x;  // float4 index
    const int p4    = idx & 1023;
    const int plane = idx >> 10;
    const int o     = plane & 255;
    const int n     = plane >> 8;

    const float4 e = ((const float4*)(ws + OFF_E + (size_t)n * 4096))[p4];
    const float  b = ws[OFF_BIAS + n * 256 + o];
    out[idx] = make_float4(e.x + b, e.y + b, e.z + b, e.w + b);
}

// ---------------------------------------------------------------- launch
extern "C" void kernel_launch(void* const* d_in, const int* in_sizes, int n_in,
                              void* d_out, int out_size, void* d_ws, size_t ws_size,
                              hipStream_t stream)
{
    const float* style     = (const float*)d_in[0];
    const float* content   = (const float*)d_in[1];
    const float* dw_w      = (const float*)d_in[2];
    const float* dw_b      = (const float*)d_in[3];
    const float* pw_kn_w   = (const float*)d_in[4];
    const float* pw_kn_b   = (const float*)d_in[5];
    const float* pw_bias_w = (const float*)d_in[6];
    const float* pw_bias_b = (const float*)d_in[7];
    float* ws  = (float*)d_ws;
    float* out = (float*)d_out;

    ada_stats<<<16,    256, 0, stream>>>(style, dw_w, dw_b, pw_kn_w, pw_kn_b,
                                         pw_bias_w, pw_bias_b, ws);
    ada_chsum<<<512,   256, 0, stream>>>(content, ws);
    ada_conv <<<16,    256, 0, stream>>>(ws);
    ada_out  <<<16384, 256, 0, stream>>>(ws, (float4*)out);
}